// Round 4
// baseline (303.215 us; speedup 1.0000x reference)
//
#include <hip/hip_runtime.h>

typedef float f32x4 __attribute__((ext_vector_type(4)));
typedef short s16x8 __attribute__((ext_vector_type(8)));

#define NB 4
#define CIN 128
#define COUT 128
#define NT 16
#define NH 64
#define NW 64
#define NTAP 27
#define KTOT (CIN * NTAP)   // 3456

// ---------- big-path geometry ----------
#define FT_H 66
#define FT_W 66
#define WMOD_BYTES (NB * NTAP * COUT * CIN * 2)              // 3,538,944
#define FT_U16 ((size_t)NB * NT * FT_H * FT_W * CIN)         // 35,684,352
#define FT_BYTES (FT_U16 * 2)                                // 71,368,704
#define WS_NEED ((size_t)WMOD_BYTES + FT_BYTES)

// conv2 tile: 2 t x 4 h x 64 w output, 128 o
#define SFT 4
#define SFH 6
#define SFW 66                       // 66*16 dwords % 32 == 0 -> bank-aligned rows
#define SFPX (SFT * SFH * SFW)       // 1584 pixels, 64 B each
#define SF_SLOTS (SFPX * 4)          // 6336 16B slots (= 99 waves, tail wave-aligned)
#define SW_U16 (COUT * 32)           // 4096 u16 = 8 KB per weight buffer

#define VMCNT1() asm volatile("s_waitcnt vmcnt(1)" ::: "memory")
#define VMCNT0() asm volatile("s_waitcnt vmcnt(0)" ::: "memory")
#define LGKM0()  asm volatile("s_waitcnt lgkmcnt(0)" ::: "memory")
#define BARRIER() asm volatile("s_barrier" ::: "memory")

__device__ __forceinline__ unsigned short f32_to_bf16(float f) {
    unsigned int u = __builtin_bit_cast(unsigned int, f);
    u += 0x7FFFu + ((u >> 16) & 1u);   // round-to-nearest-even
    return (unsigned short)(u >> 16);
}

__device__ __forceinline__ void gload16(const void* g, void* l) {
    __builtin_amdgcn_global_load_lds(
        (const __attribute__((address_space(1))) unsigned int*)g,
        (__attribute__((address_space(3))) unsigned int*)l, 16, 0, 0);
}

// ---------------- Kernel 1: weight modulation + demodulation ----------------
// Writes bf16 [b][tap][o][128ch], channel-group position XOR-swizzled by
// ((o>>1)&3) when swz!=0 (to make conv A-fragment ds_reads bank-conflict-free).
__global__ __launch_bounds__(256) void modw_kernel(
    const float* __restrict__ cond,
    const float* __restrict__ weights,
    unsigned short* __restrict__ wmod,
    int swz)
{
    int bo = blockIdx.x;
    int b = bo >> 7;
    int o = bo & 127;
    int tid = threadIdx.x;
    __shared__ float red[256];
    __shared__ float s_scale;
    const float* wrow = weights + o * KTOT;
    const float* cb = cond + b * CIN;

    float acc = 0.f;
    for (int idx = tid; idx < KTOT; idx += 256) {
        int i = idx / NTAP;
        float v = wrow[idx] * (cb[i] + 1.0f);
        acc += v * v;
    }
    red[tid] = acc;
    __syncthreads();
    #pragma unroll
    for (int s = 128; s > 0; s >>= 1) {
        if (tid < s) red[tid] += red[tid + s];
        __syncthreads();
    }
    if (tid == 0) s_scale = 1.0f / sqrtf(fmaxf(red[0], 1e-8f));
    __syncthreads();
    float scale = s_scale;
    int sw_o = swz ? ((o >> 1) & 3) : 0;

    for (int idx = tid; idx < KTOT; idx += 256) {
        int i = idx / NTAP;
        int tap = idx - i * NTAP;
        float v = wrow[idx] * (cb[i] + 1.0f) * scale;
        int pos = (i & 0x60) | ((((i >> 3) & 3) ^ sw_o) << 3) | (i & 7);
        wmod[(((b * NTAP + tap) * COUT + o) * CIN) + pos] = f32_to_bf16(v);
    }
}

// ---------------- Kernel 2: zero h/w borders of fmapT ----------------
__global__ void border_kernel(unsigned short* __restrict__ fmapT) {
    int idx = blockIdx.x * blockDim.x + threadIdx.x;  // 16B-slot granularity
    int total = NB * NT * 260 * 16;
    if (idx >= total) return;
    int slot = idx & 15;
    int pid = idx >> 4;
    int r = pid % 260;
    int bt = pid / 260;
    int hh, ww;
    if (r < 66)       { hh = 0;  ww = r; }
    else if (r < 132) { hh = 65; ww = r - 66; }
    else if (r < 196) { ww = 0;  hh = r - 131; }
    else              { ww = 65; hh = r - 195; }
    size_t p = (((size_t)bt * FT_H + hh) * FT_W + ww) * CIN + slot * 8;
    uint4 z = {0, 0, 0, 0};
    *reinterpret_cast<uint4*>(&fmapT[p]) = z;
}

// ---------------- Kernel 3: transpose+cast fmap -> padded swizzled bf16 ----------------
// fmapT[b][t][h+1][w+1][128ch], channel-group g stored at slot (g&12)|((g&3)^sw_w),
// sw_w = ((w+1)>>1)&3.
__global__ __launch_bounds__(256) void transpose_kernel(
    const float* __restrict__ fmap, unsigned short* __restrict__ fmapT)
{
    __shared__ __attribute__((aligned(16))) unsigned short sT[NW * 136];  // [w][c] pad 136
    int bid = blockIdx.x;
    int h = bid & 63;
    int t = (bid >> 6) & 15;
    int b = bid >> 10;
    int tid = threadIdx.x;

    int c = tid >> 1, wh = (tid & 1) * 32;
    const float* src = fmap + (((size_t)(b * CIN + c) * NT + t) * NH + h) * NW + wh;
    #pragma unroll
    for (int j = 0; j < 8; ++j) {
        float4 v = *reinterpret_cast<const float4*>(src + j * 4);
        int w = wh + j * 4;
        sT[(w + 0) * 136 + c] = f32_to_bf16(v.x);
        sT[(w + 1) * 136 + c] = f32_to_bf16(v.y);
        sT[(w + 2) * 136 + c] = f32_to_bf16(v.z);
        sT[(w + 3) * 136 + c] = f32_to_bf16(v.w);
    }
    __syncthreads();

    int w = tid >> 2, qq = tid & 3;
    int sw = ((w + 1) >> 1) & 3;
    size_t pixbase = (((size_t)(b * NT + t) * FT_H + (h + 1)) * FT_W + (w + 1)) * CIN;
    #pragma unroll
    for (int s = 0; s < 4; ++s) {
        int g = qq * 4 + s;
        uint4 v = *reinterpret_cast<const uint4*>(&sT[w * 136 + g * 8]);
        int slot = (g & 12) | ((g & 3) ^ sw);
        *reinterpret_cast<uint4*>(&fmapT[pixbase + slot * 8]) = v;
    }
}

// ---------------- Kernel 4: implicit-GEMM conv, counted-vmcnt pipeline ----------------
// Block: 128 o x (2 t x 4 h x 64 w) outputs. 8 waves, wave = 64 o x 128 pix.
// Weight staging: 3 rotating LDS buffers, depth-2 in flight, ONE barrier per
// k-step, s_waitcnt vmcnt(1) (never 0) in the main loop.
// NOTE: all gload16 (global_load_lds) sites must execute with FULL-wave
// (or wave-uniform) exec — the LDS dest is readfirstlane base + lane*16
// (m104/m108). t<0 halo zeroing is a separate ds_write pass AFTER the f-DMA
// retires, never a divergent branch inside the DMA loop.
__global__ __launch_bounds__(512, 2) void conv2_kernel(
    const unsigned short* __restrict__ fmapT,
    const unsigned short* __restrict__ wmod,
    float* __restrict__ out)
{
    __shared__ __attribute__((aligned(16))) unsigned short sF[SFPX * 32];   // 101376 B
    __shared__ __attribute__((aligned(16))) unsigned short sW[3][SW_U16];   // 3 x 8192 B

    int obid = blockIdx.x;
    int bid = (obid & 7) * 64 + (obid >> 3);   // XCD-contiguous swizzle (512 % 8 == 0)
    int h0 = (bid & 15) * 4;
    int t0 = ((bid >> 4) & 7) * 2;
    int b  = bid >> 7;

    int tid = threadIdx.x;
    int wv = tid >> 6;
    int l  = tid & 63;
    int lo = l & 15, hi = l >> 4;
    int obase = (wv & 1) * 64;
    int tsub  = (wv >> 1) & 1;
    int hp    = (wv >> 2) * 2;

    int swzA = (lo >> 1) & 3;

    f32x4 acc[4][2][4];
    f32x4 zz = {0.f, 0.f, 0.f, 0.f};
    #pragma unroll
    for (int a = 0; a < 4; ++a)
        #pragma unroll
        for (int h2 = 0; h2 < 2; ++h2)
            #pragma unroll
            for (int p = 0; p < 4; ++p)
                acc[a][h2][p] = zz;

    int nz = (t0 == 0) ? (2 * SFH * SFW * 4) : 0;   // 16B slots of t<0 planes

    // stage fmap chunk ic: [4t][6h][66w][4 slots x 8ch] bf16. ts<0 clamps to
    // plane 0 (garbage, overwritten by zero_t after the DMA retires).
    auto stage_f = [&](int ic) {
        #pragma unroll 1
        for (int j = 0; j < 13; ++j) {
            int s = j * 512 + tid;
            if (s < SF_SLOTS) {          // 6336 = 99 waves: guard is wave-aligned
                int px = s >> 2, q = s & 3;
                int row = px / SFW;
                int wl = px - row * SFW;
                int tl = row / SFH;
                int hl = row - tl * SFH;
                int ts = t0 + tl - 2;    // causal window t-2..t+1
                if (ts < 0) ts = 0;      // uniform gload; zeroed later
                const unsigned short* src = fmapT +
                    ((((size_t)(b * NT + ts) * FT_H + (h0 + hl)) * FT_W + wl) << 7)
                    + (ic << 5) + (q << 3);
                gload16(src, &sF[(size_t)s * 8]);
            }
        }
    };
    // flat weight stage: k-step j (0..107) -> tap j%27, chunk j/27, buffer j%3.
    // j>107 clamps to 107 (dummy reload of identical bytes; keeps vmcnt uniform).
    auto stage_w = [&](int j) {
        if (j > 107) j = 107;
        int icw = j / 27;
        int tapw = j - icw * 27;
        const unsigned short* src = wmod +
            (((size_t)(b * NTAP + tapw) * COUT + (tid >> 2)) << 7)
            + (icw << 5) + ((tid & 3) << 3);
        gload16(src, &sW[j % 3][tid * 8]);
    };
    auto zero_t = [&]() {
        uint4 z = {0, 0, 0, 0};
        for (int s = tid; s < nz; s += 512)
            *reinterpret_cast<uint4*>(&sF[(size_t)s * 8]) = z;
    };

    // prologue: chunk 0 fmap + weights for k-steps 0,1 in flight; drain once.
    stage_f(0);
    stage_w(0);
    stage_w(1);
    VMCNT0();
    if (nz) zero_t();
    LGKM0();
    BARRIER();

    int tap = 0, kt = 0, kh = 0, kw = 0, ic = 0, cur = 0;
    for (int ks = 0; ks < 108; ++ks) {
        if (tap == 0 && ks) {
            // chunk boundary: retire w(ks); ensure all waves' sF reads fully
            // returned (LGKM0) before any wave issues the overwrite DMA.
            VMCNT1(); LGKM0();
            BARRIER();
            stage_f(ic);
            stage_w(ks + 2);
            VMCNT1();              // all f slots landed; only w(ks+2) in flight
            if (nz) zero_t();      // overwrite t<0 planes (DMA already landed)
            LGKM0();
            BARRIER();
        } else {
            VMCNT1(); LGKM0();     // own w(ks) landed; lgkm already drained (~free)
            BARRIER();             // all threads' w(ks) visible; prev reads done
            stage_w(ks + 2);       // async DMA into buf (ks+2)%3, retired at ks+2
        }

        int swzB = ((lo + kw) >> 1) & 3;
        const unsigned short* wb = &sW[cur][((obase + lo) << 5) + ((hi ^ swzA) << 3)];
        s16x8 af[4];
        #pragma unroll
        for (int a = 0; a < 4; ++a)
            af[a] = *reinterpret_cast<const s16x8*>(&wb[a << 9]);

        __builtin_amdgcn_s_setprio(1);
        #pragma unroll
        for (int h2 = 0; h2 < 2; ++h2) {
            int row = (tsub + kt) * SFH + hp + h2 + kh;
            int pix = row * SFW + kw + lo;
            const unsigned short* fb = &sF[(pix << 5) + ((hi ^ swzB) << 3)];
            s16x8 bf[4];
            #pragma unroll
            for (int p = 0; p < 4; ++p)
                bf[p] = *reinterpret_cast<const s16x8*>(&fb[p << 9]);
            #pragma unroll
            for (int a = 0; a < 4; ++a)
                #pragma unroll
                for (int p = 0; p < 4; ++p)
                    acc[a][h2][p] = __builtin_amdgcn_mfma_f32_16x16x32_bf16(
                        af[a], bf[p], acc[a][h2][p], 0, 0, 0);
        }
        __builtin_amdgcn_s_setprio(0);

        // advance tap / kernel-offset / chunk counters
        ++tap; ++kw;
        if (kw == 3) { kw = 0; ++kh; if (kh == 3) { kh = 0; ++kt; } }
        if (tap == NTAP) { tap = 0; kw = 0; kh = 0; kt = 0; ++ic; }
        cur = (cur == 2) ? 0 : cur + 1;
    }

    // epilogue: D row = hi*4+reg (o), col = lo (pixel)
    int t = t0 + tsub;
    #pragma unroll
    for (int a = 0; a < 4; ++a) {
        #pragma unroll
        for (int h2 = 0; h2 < 2; ++h2) {
            int h = h0 + hp + h2;
            #pragma unroll
            for (int reg = 0; reg < 4; ++reg) {
                int o = obase + a * 16 + hi * 4 + reg;
                float* orow = out + ((((size_t)b * COUT + o) * NT + t) * NH + h) * NW;
                #pragma unroll
                for (int p = 0; p < 4; ++p)
                    orow[p * 16 + lo] = acc[a][h2][p][reg];
            }
        }
    }
}

// ---------------- Fallback (round-1 conv, used only if ws too small) ----------------
#define HB 4
#define SF_T 3
#define SF_Hf (HB + 2)
#define SF_Wf (NW + 2)
#define IPAD 40
#define SPATf (SF_T * SF_Hf * SF_Wf)

__global__ __launch_bounds__(512) void conv_kernel(
    const float* __restrict__ fmap,
    const unsigned short* __restrict__ wmod,
    float* __restrict__ out)
{
    __shared__ unsigned short sFf[SPATf * IPAD];
    __shared__ unsigned short sWf[2][COUT * IPAD];

    int bid = blockIdx.x;
    int h0 = (bid & 15) * HB;
    int t0 = (bid >> 4) & 15;
    int b  = bid >> 8;

    int tid = threadIdx.x;
    int wv = tid >> 6;
    int l  = tid & 63;
    int lo = l & 15;
    int hi = l >> 4;
    int obase = (wv & 1) * 64;
    int r = wv >> 1;

    int s_ii = tid >> 4;
    int s_ws = tid & 15;

    f32x4 acc[4][4];
    #pragma unroll
    for (int a = 0; a < 4; ++a)
        #pragma unroll
        for (int p = 0; p < 4; ++p)
            acc[a][p] = f32x4{0.f, 0.f, 0.f, 0.f};

    int tap = 0, icc = 0;
    for (int ks = 0; ks < 108; ++ks) {
        if (tap == 0) {
            if (ks) __syncthreads();
            const float* fbase = fmap + (size_t)((b * CIN + icc * 32 + s_ii) * NT) * (NH * NW);
            for (int e = s_ws; e < SPATf; e += 16) {
                int wl = e % SF_Wf;
                int rr = e / SF_Wf;
                int hl = rr % SF_Hf;
                int tl = rr / SF_Hf;
                int ts = t0 + tl - 2;
                int hs = h0 + hl - 1;
                int wsrc = wl - 1;
                float v = 0.f;
                if (ts >= 0 && (unsigned)hs < NH && (unsigned)wsrc < NW)
                    v = fbase[(ts * NH + hs) * NW + wsrc];
                sFf[e * IPAD + s_ii] = f32_to_bf16(v);
            }
            if (ks == 0) {
                int o = tid >> 2, q = tid & 3;
                const unsigned short* src =
                    wmod + (((b * NTAP + 0) * COUT + o) * CIN) + q * 8;
                *reinterpret_cast<uint4*>(&sWf[0][o * IPAD + q * 8]) =
                    *reinterpret_cast<const uint4*>(src);
            }
        }
        __syncthreads();

        if (ks + 1 < 108) {
            int ksn = ks + 1;
            int icn = ksn / 27;
            int tapn = ksn - icn * 27;
            int o = tid >> 2, q = tid & 3;
            const unsigned short* src =
                wmod + (((b * NTAP + tapn) * COUT + o) * CIN) + icn * 32 + q * 8;
            *reinterpret_cast<uint4*>(&sWf[ksn & 1][o * IPAD + q * 8]) =
                *reinterpret_cast<const uint4*>(src);
        }

        int kt = tap / 9;
        int rem = tap - kt * 9;
        int kh = rem / 3;
        int kw = rem - kh * 3;

        s16x8 af[4], bfr[4];
        #pragma unroll
        for (int a = 0; a < 4; ++a) {
            int o = obase + a * 16 + lo;
            af[a] = *reinterpret_cast<const s16x8*>(&sWf[ks & 1][o * IPAD + hi * 8]);
        }
        #pragma unroll
        for (int p = 0; p < 4; ++p) {
            int sp = (kt * SF_Hf + (r + kh)) * SF_Wf + (p * 16 + lo + kw);
            bfr[p] = *reinterpret_cast<const s16x8*>(&sFf[sp * IPAD + hi * 8]);
        }
        #pragma unroll
        for (int a = 0; a < 4; ++a)
            #pragma unroll
            for (int p = 0; p < 4; ++p)
                acc[a][p] = __builtin_amdgcn_mfma_f32_16x16x32_bf16(
                    af[a], bfr[p], acc[a][p], 0, 0, 0);

        if (++tap == 27) { tap = 0; ++icc; }
    }

    int h = h0 + r;
    #pragma unroll
    for (int a = 0; a < 4; ++a) {
        #pragma unroll
        for (int reg = 0; reg < 4; ++reg) {
            int o = obase + a * 16 + hi * 4 + reg;
            float* orow = out + ((((size_t)b * COUT + o) * NT + t0) * NH + h) * NW;
            #pragma unroll
            for (int p = 0; p < 4; ++p)
                orow[p * 16 + lo] = acc[a][p][reg];
        }
    }
}

extern "C" void kernel_launch(void* const* d_in, const int* in_sizes, int n_in,
                              void* d_out, int out_size, void* d_ws, size_t ws_size,
                              hipStream_t stream) {
    (void)in_sizes; (void)n_in; (void)out_size;
    const float* fmap    = (const float*)d_in[0];
    const float* cond    = (const float*)d_in[1];
    const float* weights = (const float*)d_in[2];
    float* outp = (float*)d_out;
    unsigned short* wmod = (unsigned short*)d_ws;

    if (ws_size >= WS_NEED) {
        unsigned short* fmapT = (unsigned short*)((char*)d_ws + WMOD_BYTES);
        modw_kernel<<<dim3(NB * COUT), dim3(256), 0, stream>>>(cond, weights, wmod, 1);
        border_kernel<<<dim3((NB * NT * 260 * 16 + 255) / 256), dim3(256), 0, stream>>>(fmapT);
        transpose_kernel<<<dim3(NB * NT * NH), dim3(256), 0, stream>>>(fmap, fmapT);
        conv2_kernel<<<dim3(NB * (NT / 2) * (NH / 4)), dim3(512), 0, stream>>>(fmapT, wmod, outp);
    } else {
        modw_kernel<<<dim3(NB * COUT), dim3(256), 0, stream>>>(cond, weights, wmod, 0);
        conv_kernel<<<dim3(NB * NT * (NH / HB)), dim3(512), 0, stream>>>(fmap, wmod, outp);
    }
}

// Round 5
// 301.956 us; speedup vs baseline: 1.0042x; 1.0042x over previous
//
#include <hip/hip_runtime.h>

typedef float f32x4 __attribute__((ext_vector_type(4)));
typedef short s16x8 __attribute__((ext_vector_type(8)));

#define NB 4
#define CIN 128
#define COUT 128
#define NT 16
#define NH 64
#define NW 64
#define NTAP 27
#define KTOT (CIN * NTAP)   // 3456

// ---------- big-path geometry ----------
#define FT_H 66
#define FT_W 66
#define WMOD_BYTES (NB * NTAP * COUT * CIN * 2)              // 3,538,944
#define FT_U16 ((size_t)NB * NT * FT_H * FT_W * CIN)         // 35,684,352
#define FT_BYTES (FT_U16 * 2)                                // 71,368,704
#define WS_NEED ((size_t)WMOD_BYTES + FT_BYTES)

// conv2 tile: 2 t x 4 h x 64 w output, 128 o
#define SFT 4
#define SFH 6
#define SFW 66                       // 66*16 dwords % 32 == 0 -> bank-aligned rows
#define SFPX (SFT * SFH * SFW)       // 1584 pixels, 64 B each
#define SF_SLOTS (SFPX * 4)          // 6336 16B slots (= 99 waves, tail wave-aligned)

#define VMCNT0() asm volatile("s_waitcnt vmcnt(0)" ::: "memory")
#define LGKM0()  asm volatile("s_waitcnt lgkmcnt(0)" ::: "memory")
#define BARRIER() asm volatile("s_barrier" ::: "memory")

__device__ __forceinline__ unsigned short f32_to_bf16(float f) {
    unsigned int u = __builtin_bit_cast(unsigned int, f);
    u += 0x7FFFu + ((u >> 16) & 1u);   // round-to-nearest-even
    return (unsigned short)(u >> 16);
}

__device__ __forceinline__ void gload16(const void* g, void* l) {
    __builtin_amdgcn_global_load_lds(
        (const __attribute__((address_space(1))) unsigned int*)g,
        (__attribute__((address_space(3))) unsigned int*)l, 16, 0, 0);
}

// ---------------- Kernel 1: weight modulation + demodulation ----------------
// Writes bf16 [b][tap][o][128ch]; optional channel-group swizzle (swz) kept
// for compat but unused now (A-frags load global->VGPR, no bank conflicts).
__global__ __launch_bounds__(256) void modw_kernel(
    const float* __restrict__ cond,
    const float* __restrict__ weights,
    unsigned short* __restrict__ wmod,
    int swz)
{
    int bo = blockIdx.x;
    int b = bo >> 7;
    int o = bo & 127;
    int tid = threadIdx.x;
    __shared__ float red[256];
    __shared__ float s_scale;
    const float* wrow = weights + o * KTOT;
    const float* cb = cond + b * CIN;

    float acc = 0.f;
    for (int idx = tid; idx < KTOT; idx += 256) {
        int i = idx / NTAP;
        float v = wrow[idx] * (cb[i] + 1.0f);
        acc += v * v;
    }
    red[tid] = acc;
    __syncthreads();
    #pragma unroll
    for (int s = 128; s > 0; s >>= 1) {
        if (tid < s) red[tid] += red[tid + s];
        __syncthreads();
    }
    if (tid == 0) s_scale = 1.0f / sqrtf(fmaxf(red[0], 1e-8f));
    __syncthreads();
    float scale = s_scale;
    int sw_o = swz ? ((o >> 1) & 3) : 0;

    for (int idx = tid; idx < KTOT; idx += 256) {
        int i = idx / NTAP;
        int tap = idx - i * NTAP;
        float v = wrow[idx] * (cb[i] + 1.0f) * scale;
        int pos = (i & 0x60) | ((((i >> 3) & 3) ^ sw_o) << 3) | (i & 7);
        wmod[(((b * NTAP + tap) * COUT + o) * CIN) + pos] = f32_to_bf16(v);
    }
}

// ---------------- Kernel 2: zero h/w borders of fmapT ----------------
__global__ void border_kernel(unsigned short* __restrict__ fmapT) {
    int idx = blockIdx.x * blockDim.x + threadIdx.x;  // 16B-slot granularity
    int total = NB * NT * 260 * 16;
    if (idx >= total) return;
    int slot = idx & 15;
    int pid = idx >> 4;
    int r = pid % 260;
    int bt = pid / 260;
    int hh, ww;
    if (r < 66)       { hh = 0;  ww = r; }
    else if (r < 132) { hh = 65; ww = r - 66; }
    else if (r < 196) { ww = 0;  hh = r - 131; }
    else              { ww = 65; hh = r - 195; }
    size_t p = (((size_t)bt * FT_H + hh) * FT_W + ww) * CIN + slot * 8;
    uint4 z = {0, 0, 0, 0};
    *reinterpret_cast<uint4*>(&fmapT[p]) = z;
}

// ---------------- Kernel 3: transpose+cast fmap -> padded swizzled bf16 ----------------
// fmapT[b][t][h+1][w+1][128ch], channel-group g stored at slot (g&12)|((g&3)^sw_w),
// sw_w = ((w+1)>>1)&3.
__global__ __launch_bounds__(256) void transpose_kernel(
    const float* __restrict__ fmap, unsigned short* __restrict__ fmapT)
{
    __shared__ __attribute__((aligned(16))) unsigned short sT[NW * 136];  // [w][c] pad 136
    int bid = blockIdx.x;
    int h = bid & 63;
    int t = (bid >> 6) & 15;
    int b = bid >> 10;
    int tid = threadIdx.x;

    int c = tid >> 1, wh = (tid & 1) * 32;
    const float* src = fmap + (((size_t)(b * CIN + c) * NT + t) * NH + h) * NW + wh;
    #pragma unroll
    for (int j = 0; j < 8; ++j) {
        float4 v = *reinterpret_cast<const float4*>(src + j * 4);
        int w = wh + j * 4;
        sT[(w + 0) * 136 + c] = f32_to_bf16(v.x);
        sT[(w + 1) * 136 + c] = f32_to_bf16(v.y);
        sT[(w + 2) * 136 + c] = f32_to_bf16(v.z);
        sT[(w + 3) * 136 + c] = f32_to_bf16(v.w);
    }
    __syncthreads();

    int w = tid >> 2, qq = tid & 3;
    int sw = ((w + 1) >> 1) & 3;
    size_t pixbase = (((size_t)(b * NT + t) * FT_H + (h + 1)) * FT_W + (w + 1)) * CIN;
    #pragma unroll
    for (int s = 0; s < 4; ++s) {
        int g = qq * 4 + s;
        uint4 v = *reinterpret_cast<const uint4*>(&sT[w * 136 + g * 8]);
        int slot = (g & 12) | ((g & 3) ^ sw);
        *reinterpret_cast<uint4*>(&fmapT[pixbase + slot * 8]) = v;
    }
}

// ---------------- Kernel 4: implicit-GEMM conv, barrier-free tap loop ----------------
// Block: 128 o x (2 t x 4 h x 64 w) outputs. 8 waves, wave = 64 o x 128 pix.
// A-fragments (weights) load DIRECTLY global->VGPR (wmod is L2-resident and
// shared by all waves) -> no sW, no per-k-step barrier. Only 4 chunk-boundary
// syncs remain (sF restage). B-fragments from swizzled sF, conflict-free.
__global__ __launch_bounds__(512, 2) void conv2_kernel(
    const unsigned short* __restrict__ fmapT,
    const unsigned short* __restrict__ wmod,
    float* __restrict__ out)
{
    __shared__ __attribute__((aligned(16))) unsigned short sF[SFPX * 32];   // 101376 B

    int obid = blockIdx.x;
    int bid = (obid & 7) * 64 + (obid >> 3);   // XCD-contiguous swizzle (512 % 8 == 0)
    int h0 = (bid & 15) * 4;
    int t0 = ((bid >> 4) & 7) * 2;
    int b  = bid >> 7;

    int tid = threadIdx.x;
    int wv = tid >> 6;
    int l  = tid & 63;
    int lo = l & 15, hi = l >> 4;
    int obase = (wv & 1) * 64;
    int tsub  = (wv >> 1) & 1;
    int hp    = (wv >> 2) * 2;

    f32x4 acc[4][2][4];
    f32x4 zz = {0.f, 0.f, 0.f, 0.f};
    #pragma unroll
    for (int a = 0; a < 4; ++a)
        #pragma unroll
        for (int h2 = 0; h2 < 2; ++h2)
            #pragma unroll
            for (int p = 0; p < 4; ++p)
                acc[a][h2][p] = zz;

    int nz = (t0 == 0) ? (2 * SFH * SFW * 4) : 0;   // 16B slots of t<0 planes

    // stage fmap chunk ic: [4t][6h][66w][4 slots x 8ch] bf16. ts<0 clamps to
    // plane 0 (garbage, overwritten by zero_t after the DMA retires).
    // FULL-WAVE exec at every gload16 (m104/m108): tail guard is wave-aligned.
    auto stage_f = [&](int ic) {
        #pragma unroll 1
        for (int j = 0; j < 13; ++j) {
            int s = j * 512 + tid;
            if (s < SF_SLOTS) {          // 6336 = 99 waves: guard is wave-aligned
                int px = s >> 2, q = s & 3;
                int row = px / SFW;
                int wl = px - row * SFW;
                int tl = row / SFH;
                int hl = row - tl * SFH;
                int ts = t0 + tl - 2;    // causal window t-2..t+1
                if (ts < 0) ts = 0;      // uniform gload; zeroed later
                const unsigned short* src = fmapT +
                    ((((size_t)(b * NT + ts) * FT_H + (h0 + hl)) * FT_W + wl) << 7)
                    + (ic << 5) + (q << 3);
                gload16(src, &sF[(size_t)s * 8]);
            }
        }
    };
    auto zero_t = [&]() {
        uint4 z = {0, 0, 0, 0};
        for (int s = tid; s < nz; s += 512)
            *reinterpret_cast<uint4*>(&sF[(size_t)s * 8]) = z;
    };

    // per-lane weight base: row (obase+lo), ch-group hi (8 ch)
    const unsigned short* wlane = wmod
        + ((size_t)b * NTAP * COUT) * CIN
        + (obase + lo) * CIN + hi * 8;

    // B fragment element offsets per kw (within a row base):
    // elem = row*SFW*32 + (kw+lo)*32 + (hi ^ ((lo+kw)>>1 & 3))*8  (+ p*512)
    int offk[3];
    #pragma unroll
    for (int kw = 0; kw < 3; ++kw)
        offk[kw] = ((kw + lo) << 5) + ((hi ^ (((lo + kw) >> 1) & 3)) << 3);

    #pragma unroll 1
    for (int ic = 0; ic < 4; ++ic) {
        if (ic) {
            LGKM0();       // this wave's sF reads fully returned
            BARRIER();     // ALL waves done with previous chunk
        }
        stage_f(ic);
        VMCNT0();          // f-DMA landed (also drains any A prefetch: safe)
        if (nz) zero_t();
        LGKM0();
        BARRIER();         // sF chunk published

        const unsigned short* wch = wlane + (ic << 5);
        #pragma unroll 1
        for (int kt = 0; kt < 3; ++kt) {
            const unsigned short* wkt = wch + (size_t)kt * 9 * COUT * CIN;
            int rb = ((tsub + kt) * SFH + hp) * (SFW * 32);
            #pragma unroll
            for (int kh = 0; kh < 3; ++kh) {
                #pragma unroll
                for (int kw = 0; kw < 3; ++kw) {
                    const unsigned short* wtap = wkt + (kh * 3 + kw) * (COUT * CIN);
                    s16x8 af[4];
                    #pragma unroll
                    for (int a = 0; a < 4; ++a)
                        af[a] = *reinterpret_cast<const s16x8*>(wtap + a * 16 * CIN);

                    __builtin_amdgcn_s_setprio(1);
                    #pragma unroll
                    for (int h2 = 0; h2 < 2; ++h2) {
                        int eb = rb + (h2 + kh) * (SFW * 32) + offk[kw];
                        s16x8 bf[4];
                        #pragma unroll
                        for (int p = 0; p < 4; ++p)
                            bf[p] = *reinterpret_cast<const s16x8*>(&sF[eb + p * 512]);
                        #pragma unroll
                        for (int a = 0; a < 4; ++a)
                            #pragma unroll
                            for (int p = 0; p < 4; ++p)
                                acc[a][h2][p] = __builtin_amdgcn_mfma_f32_16x16x32_bf16(
                                    af[a], bf[p], acc[a][h2][p], 0, 0, 0);
                    }
                    __builtin_amdgcn_s_setprio(0);
                }
            }
        }
    }

    // epilogue: D row = hi*4+reg (o), col = lo (pixel)
    int t = t0 + tsub;
    #pragma unroll
    for (int a = 0; a < 4; ++a) {
        #pragma unroll
        for (int h2 = 0; h2 < 2; ++h2) {
            int h = h0 + hp + h2;
            #pragma unroll
            for (int reg = 0; reg < 4; ++reg) {
                int o = obase + a * 16 + hi * 4 + reg;
                float* orow = out + ((((size_t)b * COUT + o) * NT + t) * NH + h) * NW;
                #pragma unroll
                for (int p = 0; p < 4; ++p)
                    orow[p * 16 + lo] = acc[a][h2][p][reg];
            }
        }
    }
}

// ---------------- Fallback (round-1 conv, used only if ws too small) ----------------
#define HB 4
#define SF_T 3
#define SF_Hf (HB + 2)
#define SF_Wf (NW + 2)
#define IPAD 40
#define SPATf (SF_T * SF_Hf * SF_Wf)

__global__ __launch_bounds__(512) void conv_kernel(
    const float* __restrict__ fmap,
    const unsigned short* __restrict__ wmod,
    float* __restrict__ out)
{
    __shared__ unsigned short sFf[SPATf * IPAD];
    __shared__ unsigned short sWf[2][COUT * IPAD];

    int bid = blockIdx.x;
    int h0 = (bid & 15) * HB;
    int t0 = (bid >> 4) & 15;
    int b  = bid >> 8;

    int tid = threadIdx.x;
    int wv = tid >> 6;
    int l  = tid & 63;
    int lo = l & 15;
    int hi = l >> 4;
    int obase = (wv & 1) * 64;
    int r = wv >> 1;

    int s_ii = tid >> 4;
    int s_ws = tid & 15;

    f32x4 acc[4][4];
    #pragma unroll
    for (int a = 0; a < 4; ++a)
        #pragma unroll
        for (int p = 0; p < 4; ++p)
            acc[a][p] = f32x4{0.f, 0.f, 0.f, 0.f};

    int tap = 0, icc = 0;
    for (int ks = 0; ks < 108; ++ks) {
        if (tap == 0) {
            if (ks) __syncthreads();
            const float* fbase = fmap + (size_t)((b * CIN + icc * 32 + s_ii) * NT) * (NH * NW);
            for (int e = s_ws; e < SPATf; e += 16) {
                int wl = e % SF_Wf;
                int rr = e / SF_Wf;
                int hl = rr % SF_Hf;
                int tl = rr / SF_Hf;
                int ts = t0 + tl - 2;
                int hs = h0 + hl - 1;
                int wsrc = wl - 1;
                float v = 0.f;
                if (ts >= 0 && (unsigned)hs < NH && (unsigned)wsrc < NW)
                    v = fbase[(ts * NH + hs) * NW + wsrc];
                sFf[e * IPAD + s_ii] = f32_to_bf16(v);
            }
            if (ks == 0) {
                int o = tid >> 2, q = tid & 3;
                const unsigned short* src =
                    wmod + (((b * NTAP + 0) * COUT + o) * CIN) + q * 8;
                *reinterpret_cast<uint4*>(&sWf[0][o * IPAD + q * 8]) =
                    *reinterpret_cast<const uint4*>(src);
            }
        }
        __syncthreads();

        if (ks + 1 < 108) {
            int ksn = ks + 1;
            int icn = ksn / 27;
            int tapn = ksn - icn * 27;
            int o = tid >> 2, q = tid & 3;
            const unsigned short* src =
                wmod + (((b * NTAP + tapn) * COUT + o) * CIN) + icn * 32 + q * 8;
            *reinterpret_cast<uint4*>(&sWf[ksn & 1][o * IPAD + q * 8]) =
                *reinterpret_cast<const uint4*>(src);
        }

        int kt = tap / 9;
        int rem = tap - kt * 9;
        int kh = rem / 3;
        int kw = rem - kh * 3;

        s16x8 af[4], bfr[4];
        #pragma unroll
        for (int a = 0; a < 4; ++a) {
            int o = obase + a * 16 + lo;
            af[a] = *reinterpret_cast<const s16x8*>(&sWf[ks & 1][o * IPAD + hi * 8]);
        }
        #pragma unroll
        for (int p = 0; p < 4; ++p) {
            int sp = (kt * SF_Hf + (r + kh)) * SF_Wf + (p * 16 + lo + kw);
            bfr[p] = *reinterpret_cast<const s16x8*>(&sFf[sp * IPAD + hi * 8]);
        }
        #pragma unroll
        for (int a = 0; a < 4; ++a)
            #pragma unroll
            for (int p = 0; p < 4; ++p)
                acc[a][p] = __builtin_amdgcn_mfma_f32_16x16x32_bf16(
                    af[a], bfr[p], acc[a][p], 0, 0, 0);

        if (++tap == 27) { tap = 0; ++icc; }
    }

    int h = h0 + r;
    #pragma unroll
    for (int a = 0; a < 4; ++a) {
        #pragma unroll
        for (int reg = 0; reg < 4; ++reg) {
            int o = obase + a * 16 + hi * 4 + reg;
            float* orow = out + ((((size_t)b * COUT + o) * NT + t0) * NH + h) * NW;
            #pragma unroll
            for (int p = 0; p < 4; ++p)
                orow[p * 16 + lo] = acc[a][p][reg];
        }
    }
}

extern "C" void kernel_launch(void* const* d_in, const int* in_sizes, int n_in,
                              void* d_out, int out_size, void* d_ws, size_t ws_size,
                              hipStream_t stream) {
    (void)in_sizes; (void)n_in; (void)out_size;
    const float* fmap    = (const float*)d_in[0];
    const float* cond    = (const float*)d_in[1];
    const float* weights = (const float*)d_in[2];
    float* outp = (float*)d_out;
    unsigned short* wmod = (unsigned short*)d_ws;

    if (ws_size >= WS_NEED) {
        unsigned short* fmapT = (unsigned short*)((char*)d_ws + WMOD_BYTES);
        modw_kernel<<<dim3(NB * COUT), dim3(256), 0, stream>>>(cond, weights, wmod, 0);
        border_kernel<<<dim3((NB * NT * 260 * 16 + 255) / 256), dim3(256), 0, stream>>>(fmapT);
        transpose_kernel<<<dim3(NB * NT * NH), dim3(256), 0, stream>>>(fmap, fmapT);
        conv2_kernel<<<dim3(NB * (NT / 2) * (NH / 4)), dim3(512), 0, stream>>>(fmapT, wmod, outp);
    } else {
        modw_kernel<<<dim3(NB * COUT), dim3(256), 0, stream>>>(cond, weights, wmod, 0);
        conv_kernel<<<dim3(NB * NT * (NH / HB)), dim3(512), 0, stream>>>(fmap, wmod, outp);
    }
}